// Round 11
// baseline (2182.075 us; speedup 1.0000x reference)
//
#include <hip/hip_runtime.h>

// SimpleLSTM persistent kernel, r8 redesign: 256 WGs (one per batch element),
// 256 threads each (4 waves = 1 wave/SIMD). Thread j owns ALL FOUR gate rows of
// hidden unit j ({j, j+256, j+512, j+768} = i,f,g,o) -> no cross-thread gate
// exchange at all. W_hh k[0,192) in VGPRs (4 rows x 96 h2 = 384 regs),
// k[192,256) in LDS chunk-major (verified 0 bank conflicts in r7/r8).
// Why 256 threads: VGPR budget stuck at 128 for every 512-thread spelling
// (launch_bounds(512,2), bare attrs — 3 rounds of evidence). launch_bounds(256,1)
// yields a 512-VGPR budget under BOTH the CUDA (1 block/CU) and AMD (1 wave/EU)
// readings, and 1 wave/SIMD is the HW cap anyway for a 4-wave WG at >256 regs.

typedef _Float16 h16;
typedef _Float16 h2_t __attribute__((ext_vector_type(2)));
typedef _Float16 h8_t __attribute__((ext_vector_type(8)));

#if defined(__has_builtin)
#  if __has_builtin(__builtin_amdgcn_fdot2)
#    define FDOT2(a, b, c) __builtin_amdgcn_fdot2((a), (b), (c), false)
#  endif
#endif
#ifndef FDOT2
__device__ __forceinline__ float fdot2_sw(h2_t a, h2_t b, float c) {
  return c + (float)a.x * (float)b.x + (float)a.y * (float)b.y;
}
#  define FDOT2(a, b, c) fdot2_sw((a), (b), (c))
#endif

__device__ __forceinline__ float fast_sigmoid(float x) {
  return __builtin_amdgcn_rcpf(1.0f + __builtin_amdgcn_exp2f(-1.44269504f * x));
}
__device__ __forceinline__ float fast_tanh(float x) {
  return 1.0f - 2.0f * __builtin_amdgcn_rcpf(1.0f + __builtin_amdgcn_exp2f(2.88539008f * x));
}

union V8 { h8_t v; h2_t p[4]; };

#define NSTEPS 512
#define KRREG  192                  // k-range held in VGPRs per gate-row
#define RC     (KRREG / 8)          // 24 register chunks of 8 halfs
#define LC     ((256 - KRREG) / 8)  // 8 LDS chunks of 8 halfs
#define ROWS   4                    // gate rows per thread (i,f,g,o of unit t)

__global__ void __launch_bounds__(256, 1) lstm_persist(
    const float* __restrict__ X, const float* __restrict__ W_ih,
    const float* __restrict__ W_hh, const float* __restrict__ b_ih,
    const float* __restrict__ b_hh, const float* __restrict__ W_dense,
    const float* __restrict__ b_dense, float* __restrict__ out) {
  // Chunk-major: wlds8[c][r] = halfs [KRREG+8c, KRREG+8c+8) of W_hh row r.
  // For fixed c, lane reads wlds8[c][t + 256*ri] -> 64 lanes span 1024
  // contiguous bytes -> conflict-free (SQ_LDS_BANK_CONFLICT == 0, measured).
  __shared__ h8_t wlds8[LC][1024];  // 128 KiB
  __shared__ h8_t hbuf8[32];        // h_t as f16 (256 halfs)
  __shared__ float red[4][3];       // dense-head wave partials

  const int t = threadIdx.x;  // 0..255: hidden unit index
  const int b = blockIdx.x;   // batch element

  // ---------------- init: pack weights ----------------
  h2_t wreg[ROWS][KRREG / 2];  // 384 VGPRs of f16 pairs
#pragma unroll
  for (int ri = 0; ri < ROWS; ++ri) {
    const float* wr = W_hh + (size_t)(t + ri * 256) * 256;
#pragma unroll
    for (int kk = 0; kk < RC; ++kk) {
      float4 a = ((const float4*)wr)[kk * 2];
      float4 c4 = ((const float4*)wr)[kk * 2 + 1];
      h2_t w0; w0.x = (h16)a.x;  w0.y = (h16)a.y;
      h2_t w1; w1.x = (h16)a.z;  w1.y = (h16)a.w;
      h2_t w2; w2.x = (h16)c4.x; w2.y = (h16)c4.y;
      h2_t w3; w3.x = (h16)c4.z; w3.y = (h16)c4.w;
      wreg[ri][kk * 4 + 0] = w0;
      wreg[ri][kk * 4 + 1] = w1;
      wreg[ri][kk * 4 + 2] = w2;
      wreg[ri][kk * 4 + 3] = w3;
    }
  }
  // LDS tail of W_hh, chunk-major
#pragma unroll
  for (int ri = 0; ri < ROWS; ++ri) {
    const int r = t + ri * 256;
    const float* wr = W_hh + (size_t)r * 256 + KRREG;
#pragma unroll
    for (int c = 0; c < LC; ++c) {
      float4 a = ((const float4*)wr)[c * 2];
      float4 d = ((const float4*)wr)[c * 2 + 1];
      h8_t w8;
      w8[0] = (h16)a.x; w8[1] = (h16)a.y; w8[2] = (h16)a.z; w8[3] = (h16)a.w;
      w8[4] = (h16)d.x; w8[5] = (h16)d.y; w8[6] = (h16)d.z; w8[7] = (h16)d.w;
      wlds8[c][r] = w8;
    }
  }
  // W_ih rows as f16 pairs (F=10 -> 5 pairs per row)
  h2_t wih[ROWS][5];
#pragma unroll
  for (int ri = 0; ri < ROWS; ++ri) {
    const float* wr = W_ih + (size_t)(t + ri * 256) * 10;
#pragma unroll
    for (int p = 0; p < 5; ++p) {
      h2_t w; w.x = (h16)wr[2 * p]; w.y = (h16)wr[2 * p + 1];
      wih[ri][p] = w;
    }
  }
  float bias[ROWS];
#pragma unroll
  for (int ri = 0; ri < ROWS; ++ri)
    bias[ri] = b_ih[t + ri * 256] + b_hh[t + ri * 256];

  const float wd0 = W_dense[t];        // W_dense[0][t]
  const float wd1 = W_dense[256 + t];  // W_dense[1][t]
  const float wd2 = W_dense[512 + t];  // W_dense[2][t]
  float bd = 0.f, c_state = 0.f;
  if (t < 3) bd = b_dense[t];
  ((h16*)hbuf8)[t] = (h16)0.f;  // h0 = 0 (256 threads cover all 256 halfs)

  const float* Xb = X + (size_t)b * (NSTEPS * 10);
  float* outb = out + (size_t)b * (NSTEPS * 3);

  __syncthreads();

  // ---------------- time loop ----------------
  for (int step = 0; step < NSTEPS; ++step) {
    // Phase A: 4 gate pre-activations, 4 independent acc chains (ILP=4).
    float a0 = bias[0], a1 = bias[1], a2 = bias[2], a3 = bias[3];

    {  // input projection; x_t is workgroup-uniform (scalar-cached)
      const float* xp = Xb + step * 10;
#pragma unroll
      for (int p = 0; p < 5; ++p) {
        h2_t xh; xh.x = (h16)xp[2 * p]; xh.y = (h16)xp[2 * p + 1];
        a0 = FDOT2(xh, wih[0][p], a0);
        a1 = FDOT2(xh, wih[1][p], a1);
        a2 = FDOT2(xh, wih[2][p], a2);
        a3 = FDOT2(xh, wih[3][p], a3);
      }
    }
    // register-resident k in [0,192): each h-chunk reused by all 4 rows
#pragma unroll
    for (int kk = 0; kk < RC; ++kk) {
      V8 u; u.v = hbuf8[kk];  // broadcast read
#pragma unroll
      for (int p = 0; p < 4; ++p) {
        a0 = FDOT2(u.p[p], wreg[0][kk * 4 + p], a0);
        a1 = FDOT2(u.p[p], wreg[1][kk * 4 + p], a1);
        a2 = FDOT2(u.p[p], wreg[2][kk * 4 + p], a2);
        a3 = FDOT2(u.p[p], wreg[3][kk * 4 + p], a3);
      }
    }
    // LDS-resident k in [192,256)
#pragma unroll
    for (int c = 0; c < LC; ++c) {
      V8 u; u.v = hbuf8[RC + c];        // broadcast read
      V8 w0; w0.v = wlds8[c][t];        // 64 lanes x 16B contiguous
      V8 w1; w1.v = wlds8[c][t + 256];
      V8 w2; w2.v = wlds8[c][t + 512];
      V8 w3; w3.v = wlds8[c][t + 768];
#pragma unroll
      for (int p = 0; p < 4; ++p) {
        a0 = FDOT2(u.p[p], w0.p[p], a0);
        a1 = FDOT2(u.p[p], w1.p[p], a1);
        a2 = FDOT2(u.p[p], w2.p[p], a2);
        a3 = FDOT2(u.p[p], w3.p[p], a3);
      }
    }

    // Phase B: all four gates are thread-local (rows t, t+256, t+512, t+768
    // = i,f,g,o of unit t) -> no exchange.
    const float ig = fast_sigmoid(a0);
    const float fg = fast_sigmoid(a1);
    const float gg = fast_tanh(a2);
    const float og = fast_sigmoid(a3);
    c_state = fg * c_state + ig * gg;
    const float h = og * fast_tanh(c_state);

    __syncthreads();  // [1] all hbuf reads of this step complete
    ((h16*)hbuf8)[t] = (h16)h;
    // dense head: 3 dot products over the 256 hidden units
    float p0 = h * wd0, p1 = h * wd1, p2 = h * wd2;
#pragma unroll
    for (int m = 32; m > 0; m >>= 1) {
      p0 += __shfl_xor(p0, m);
      p1 += __shfl_xor(p1, m);
      p2 += __shfl_xor(p2, m);
    }
    if ((t & 63) == 0) {
      red[t >> 6][0] = p0; red[t >> 6][1] = p1; red[t >> 6][2] = p2;
    }
    __syncthreads();  // [2] h_{t+1} + head partials visible
    if (t < 3) {
      outb[step * 3 + t] = red[0][t] + red[1][t] + red[2][t] + red[3][t] + bd;
    }
  }
}

extern "C" void kernel_launch(void* const* d_in, const int* in_sizes, int n_in,
                              void* d_out, int out_size, void* d_ws, size_t ws_size,
                              hipStream_t stream) {
  const float* X       = (const float*)d_in[0];
  const float* W_ih    = (const float*)d_in[1];
  const float* W_hh    = (const float*)d_in[2];
  const float* b_ih    = (const float*)d_in[3];
  const float* b_hh    = (const float*)d_in[4];
  const float* W_dense = (const float*)d_in[5];
  const float* b_dense = (const float*)d_in[6];
  lstm_persist<<<dim3(256), dim3(256), 0, stream>>>(
      X, W_ih, W_hh, b_ih, b_hh, W_dense, b_dense, (float*)d_out);
}

// Round 12
// 1420.806 us; speedup vs baseline: 1.5358x; 1.5358x over previous
//
#include <hip/hip_runtime.h>

// SimpleLSTM persistent kernel: 256 WGs (one per batch element), 512 threads each.
// W_hh held on-CU as f16: k[0,192) in VGPRs (2 rows x 96 pairs = 192 regs),
// k[192,256) in LDS chunk-major (verified 0 bank conflicts). fdot2 MACs, f32 acc.
// R11 learning: VALU-addressable VGPR ceiling is 256 (v0-v255); the 512-reg
// unified file is VGPR+AGPR and hipcc won't AGPR-spill here. 4-row/256-thread
// design (384 wreg) can never fit -> back to 2-row/512-thread (192 wreg + ~45
// working = ~237 <= 256). The budget lever PROVEN in r11: __launch_bounds__(N,1)
// raises the cap (128->256). For 512 threads: 1 WG/CU = 2 waves/SIMD = full RF.

typedef _Float16 h16;
typedef _Float16 h2_t __attribute__((ext_vector_type(2)));
typedef _Float16 h8_t __attribute__((ext_vector_type(8)));

#if defined(__has_builtin)
#  if __has_builtin(__builtin_amdgcn_fdot2)
#    define FDOT2(a, b, c) __builtin_amdgcn_fdot2((a), (b), (c), false)
#  endif
#endif
#ifndef FDOT2
__device__ __forceinline__ float fdot2_sw(h2_t a, h2_t b, float c) {
  return c + (float)a.x * (float)b.x + (float)a.y * (float)b.y;
}
#  define FDOT2(a, b, c) fdot2_sw((a), (b), (c))
#endif

__device__ __forceinline__ float fast_sigmoid(float x) {
  return __builtin_amdgcn_rcpf(1.0f + __builtin_amdgcn_exp2f(-1.44269504f * x));
}
__device__ __forceinline__ float fast_tanh(float x) {
  return 1.0f - 2.0f * __builtin_amdgcn_rcpf(1.0f + __builtin_amdgcn_exp2f(2.88539008f * x));
}

union V8 { h8_t v; h2_t p[4]; };

#define NSTEPS 512
#define KRREG  192            // k-range in VGPRs per gate-row
#define RC     (KRREG / 8)    // 24 register chunks of 8
#define LC     ((256 - KRREG) / 8)  // 8 LDS chunks of 8

__global__ void __launch_bounds__(512, 1) lstm_persist(
    const float* __restrict__ X, const float* __restrict__ W_ih,
    const float* __restrict__ W_hh, const float* __restrict__ b_ih,
    const float* __restrict__ b_hh, const float* __restrict__ W_dense,
    const float* __restrict__ b_dense, float* __restrict__ out) {
  // Chunk-major: wlds8[c][r] = halfs [KRREG+8c, KRREG+8c+8) of W_hh row r.
  // For fixed c, lane t reads wlds8[c][t] -> 64 lanes span 1024 contiguous B
  // -> conflict-free (verified: SQ_LDS_BANK_CONFLICT == 0 in r7/r8/r11).
  __shared__ h8_t wlds8[LC][1024];   // 128 KiB
  __shared__ h8_t hbuf8[32];         // h_t as f16 (256 halfs)
  __shared__ float fo_lds[512];      // f gates [0,256), o gates [256,512)
  __shared__ float red[4][3];        // dense-head wave partials

  const int t = threadIdx.x;   // 0..511; owns gate rows t and t+512
  const int b = blockIdx.x;    // batch element

  // ---------------- init: pack weights ----------------
  h2_t wreg[2][KRREG / 2];  // 192 VGPRs of f16 pairs
#pragma unroll
  for (int row = 0; row < 2; ++row) {
    const float* wr = W_hh + (size_t)(t + row * 512) * 256;
#pragma unroll
    for (int kk = 0; kk < RC; ++kk) {
      float4 a = ((const float4*)wr)[kk * 2];
      float4 c4 = ((const float4*)wr)[kk * 2 + 1];
      h2_t w0; w0.x = (h16)a.x;  w0.y = (h16)a.y;
      h2_t w1; w1.x = (h16)a.z;  w1.y = (h16)a.w;
      h2_t w2; w2.x = (h16)c4.x; w2.y = (h16)c4.y;
      h2_t w3; w3.x = (h16)c4.z; w3.y = (h16)c4.w;
      wreg[row][kk * 4 + 0] = w0;
      wreg[row][kk * 4 + 1] = w1;
      wreg[row][kk * 4 + 2] = w2;
      wreg[row][kk * 4 + 3] = w3;
    }
  }
  // LDS tail of W_hh, chunk-major
#pragma unroll
  for (int row = 0; row < 2; ++row) {
    const int r = t + row * 512;
    const float* wr = W_hh + (size_t)r * 256 + KRREG;
#pragma unroll
    for (int c = 0; c < LC; ++c) {
      float4 a = ((const float4*)wr)[c * 2];
      float4 d = ((const float4*)wr)[c * 2 + 1];
      h8_t w8;
      w8[0] = (h16)a.x; w8[1] = (h16)a.y; w8[2] = (h16)a.z; w8[3] = (h16)a.w;
      w8[4] = (h16)d.x; w8[5] = (h16)d.y; w8[6] = (h16)d.z; w8[7] = (h16)d.w;
      wlds8[c][r] = w8;
    }
  }
  // W_ih rows as f16 pairs (F=10 -> 5 pairs per row)
  h2_t wih[2][5];
#pragma unroll
  for (int row = 0; row < 2; ++row) {
    const float* wr = W_ih + (size_t)(t + row * 512) * 10;
#pragma unroll
    for (int p = 0; p < 5; ++p) {
      h2_t w; w.x = (h16)wr[2 * p]; w.y = (h16)wr[2 * p + 1];
      wih[row][p] = w;
    }
  }
  const float bias0 = b_ih[t] + b_hh[t];
  const float bias1 = b_ih[t + 512] + b_hh[t + 512];
  float wd0 = 0.f, wd1 = 0.f, wd2 = 0.f, bd = 0.f, c_state = 0.f;
  if (t < 256) {
    wd0 = W_dense[t];
    wd1 = W_dense[256 + t];
    wd2 = W_dense[512 + t];
    ((h16*)hbuf8)[t] = (h16)0.f;  // h0 = 0
  }
  if (t < 3) bd = b_dense[t];

  const float* Xb = X + (size_t)b * (NSTEPS * 10);
  float* outb = out + (size_t)b * (NSTEPS * 3);

  __syncthreads();

  // ---------------- time loop ----------------
  for (int step = 0; step < NSTEPS; ++step) {
    // Phase A: gates for rows t (acc0) and t+512 (acc1); split accumulators
    // relax the fdot2 dependency chain.
    float acc0[2]; acc0[0] = bias0; acc0[1] = 0.f;
    float acc1[2]; acc1[0] = bias1; acc1[1] = 0.f;

    {  // input projection; x_t is workgroup-uniform (scalar-cached)
      const float* xp = Xb + step * 10;
#pragma unroll
      for (int p = 0; p < 5; ++p) {
        h2_t xh; xh.x = (h16)xp[2 * p]; xh.y = (h16)xp[2 * p + 1];
        acc0[0] = FDOT2(xh, wih[0][p], acc0[0]);
        acc1[0] = FDOT2(xh, wih[1][p], acc1[0]);
      }
    }
    // register-resident k in [0,192)
#pragma unroll
    for (int kk = 0; kk < RC; ++kk) {
      V8 u; u.v = hbuf8[kk];  // broadcast read
      const int pa = kk & 1;
#pragma unroll
      for (int p = 0; p < 4; ++p) {
        acc0[pa] = FDOT2(u.p[p], wreg[0][kk * 4 + p], acc0[pa]);
        acc1[pa] = FDOT2(u.p[p], wreg[1][kk * 4 + p], acc1[pa]);
      }
    }
    // LDS-resident k in [192,256)
#pragma unroll
    for (int c = 0; c < LC; ++c) {
      V8 u; u.v = hbuf8[RC + c];       // broadcast read
      V8 w0; w0.v = wlds8[c][t];       // contiguous across lanes
      V8 w1; w1.v = wlds8[c][t + 512];
      const int pa = c & 1;
#pragma unroll
      for (int p = 0; p < 4; ++p) {
        acc0[pa] = FDOT2(u.p[p], w0.p[p], acc0[pa]);
        acc1[pa] = FDOT2(u.p[p], w1.p[p], acc1[pa]);
      }
    }
    const float g0 = acc0[0] + acc0[1];
    const float g1 = acc1[0] + acc1[1];

    // Phase B: threads >=256 publish f,o; threads <256 own (i,g) locally.
    if (t >= 256) {
      fo_lds[t - 256] = g0;  // f_{t-256}
      fo_lds[t] = g1;        // o_{t-256} at [256 + j]
    }
    __syncthreads();  // [1] fo visible; all hbuf reads of this step complete
    if (t < 256) {
      const float ig = fast_sigmoid(g0);
      const float gg = fast_tanh(g1);
      const float fg = fast_sigmoid(fo_lds[t]);
      const float og = fast_sigmoid(fo_lds[256 + t]);
      c_state = fg * c_state + ig * gg;
      const float h = og * fast_tanh(c_state);
      ((h16*)hbuf8)[t] = (h16)h;  // safe: all readers passed barrier [1]
      // dense head: 3 dot products over the 256 hidden units
      float p0 = h * wd0, p1 = h * wd1, p2 = h * wd2;
#pragma unroll
      for (int m = 32; m > 0; m >>= 1) {
        p0 += __shfl_xor(p0, m);
        p1 += __shfl_xor(p1, m);
        p2 += __shfl_xor(p2, m);
      }
      if ((t & 63) == 0) {
        red[t >> 6][0] = p0; red[t >> 6][1] = p1; red[t >> 6][2] = p2;
      }
    }
    __syncthreads();  // [2] h_{t+1} + head partials visible
    if (t < 3) {
      outb[step * 3 + t] = red[0][t] + red[1][t] + red[2][t] + red[3][t] + bd;
    }
  }
}

extern "C" void kernel_launch(void* const* d_in, const int* in_sizes, int n_in,
                              void* d_out, int out_size, void* d_ws, size_t ws_size,
                              hipStream_t stream) {
  const float* X       = (const float*)d_in[0];
  const float* W_ih    = (const float*)d_in[1];
  const float* W_hh    = (const float*)d_in[2];
  const float* b_ih    = (const float*)d_in[3];
  const float* b_hh    = (const float*)d_in[4];
  const float* W_dense = (const float*)d_in[5];
  const float* b_dense = (const float*)d_in[6];
  lstm_persist<<<dim3(256), dim3(512), 0, stream>>>(
      X, W_ih, W_hh, b_ih, b_hh, W_dense, b_dense, (float*)d_out);
}